// Round 1
// baseline (1402.488 us; speedup 1.0000x reference)
//
#include <hip/hip_runtime.h>

typedef unsigned short u16;
typedef __bf16 bf16x8 __attribute__((ext_vector_type(8)));
typedef float f32x4 __attribute__((ext_vector_type(4)));

#define TOKENS 200704
#define QK_ELEMS 51380224UL   // 32768 pairs * 49 * 32
#define V_OFF    102760448UL  // 2 * QK_ELEMS
#define R_ELEMS  169869312UL  // V_OFF + 32768*32*64

__device__ __forceinline__ u16 f2b(float f) {
    union { float f; unsigned u; } c; c.f = f;
    unsigned u = c.u;
    u += 0x7fffu + ((u >> 16) & 1u);   // round-to-nearest-even
    return (u16)(u >> 16);
}

#define GLDS(g, l) __builtin_amdgcn_global_load_lds( \
    (const __attribute__((address_space(1))) void*)(g), \
    (__attribute__((address_space(3))) void*)(l), 16, 0, 0)

// ---------------------------------------------------------------------------
// GEMM: C[m,n] = sum_k A[m,k] * W[n,k]  (A bf16 MxK row-major, W bf16 NxK row-major)
// 128x128 tile, BK=64, 256 threads (4 waves, 2x2), each wave 64x64 (4x4 frags).
// EPI 0: qkv scatter (+bias, q pre-scaled)   EPI 1: proj (+bias +x residual -> f32 out)
// EPI 2: fc1 (+bias, exact GELU -> bf16)     EPI 3: fc2 (+bias, out += )
// ---------------------------------------------------------------------------
template<int EPI>
__global__ __launch_bounds__(256)
void gemm_bt(const u16* __restrict__ A, const u16* __restrict__ W,
             const float* __restrict__ bias, int nt, int K,
             u16* __restrict__ outb, float* __restrict__ outf,
             const float* __restrict__ res)
{
    __shared__ u16 As[128 * 64];
    __shared__ u16 Bs[128 * 64];
    const int tid  = threadIdx.x;
    const int wave = tid >> 6, lane = tid & 63;
    const int bm = blockIdx.x / nt, bn = blockIdx.x % nt;
    const long m0 = (long)bm * 128;
    const int  n0 = bn * 128;
    const int wm = (wave >> 1) * 64, wn = (wave & 1) * 64;
    const int lr = lane & 15, lg = lane >> 4;
    const int crow = lane >> 3;          // row within 8-row chunk
    const int ccol = (lane & 7) * 8;     // element col within BK

    f32x4 acc[4][4] = {};

    for (int k0 = 0; k0 < K; k0 += 64) {
#pragma unroll
        for (int p = 0; p < 4; ++p) {
            const int i = wave * 4 + p;          // chunk 0..15 (wave-uniform)
            const int row = i * 8 + crow;
            GLDS(A + (m0 + row) * (long)K + k0 + ccol, As + i * 512);
            GLDS(W + (long)(n0 + row) * K + k0 + ccol, Bs + i * 512);
        }
        __syncthreads();
#pragma unroll
        for (int kk = 0; kk < 64; kk += 32) {
            bf16x8 af[4], bfr[4];
#pragma unroll
            for (int fm = 0; fm < 4; ++fm)
                af[fm] = *reinterpret_cast<const bf16x8*>(As + (wm + fm * 16 + lr) * 64 + kk + lg * 8);
#pragma unroll
            for (int fn = 0; fn < 4; ++fn)
                bfr[fn] = *reinterpret_cast<const bf16x8*>(Bs + (wn + fn * 16 + lr) * 64 + kk + lg * 8);
#pragma unroll
            for (int fm = 0; fm < 4; ++fm)
#pragma unroll
                for (int fn = 0; fn < 4; ++fn)
                    acc[fm][fn] = __builtin_amdgcn_mfma_f32_16x16x32_bf16(af[fm], bfr[fn], acc[fm][fn], 0, 0, 0);
        }
        __syncthreads();
    }

#pragma unroll
    for (int fm = 0; fm < 4; ++fm) {
#pragma unroll
        for (int r = 0; r < 4; ++r) {
            const long m = m0 + wm + fm * 16 + lg * 4 + r;
#pragma unroll
            for (int fn = 0; fn < 4; ++fn) {
                const int n = n0 + wn + fn * 16 + lr;
                const float v = acc[fm][fn][r];
                if (EPI == 0) {
                    const int mm = (int)m;
                    const int b = mm / 50176;
                    const int rem = mm % 50176;
                    const int y = rem / 224, x = rem % 224;
                    const int win = (b * 32 + y / 7) * 32 + x / 7;
                    const int pos = (y % 7) * 7 + (x % 7);
                    const int sec = n >> 8, hd = (n >> 5) & 7, d = n & 31;
                    const size_t pair = (size_t)win * 8 + hd;
                    const float val = v + bias[n];
                    if (sec == 0)
                        outb[(pair * 49 + pos) * 32 + d] = f2b(val * 0.17677669529663687f);
                    else if (sec == 1)
                        outb[QK_ELEMS + (pair * 49 + pos) * 32 + d] = f2b(val);
                    else
                        outb[V_OFF + (pair * 32 + d) * 64 + pos] = f2b(val);
                } else if (EPI == 1) {
                    outf[m * 256 + n] = v + bias[n] + res[m * 256 + n];
                } else if (EPI == 2) {
                    const float t = v + bias[n];
                    const float g = 0.5f * t * (1.0f + erff(t * 0.7071067811865476f));
                    outb[m * 1024 + n] = f2b(g);
                } else {
                    outf[m * 256 + n] += v + bias[n];
                }
            }
        }
    }
}

// ---------------------------------------------------------------------------
// LayerNorm over C=256, f32 in -> bf16 out. 1 wave per token, 4 tokens/block.
// ---------------------------------------------------------------------------
__global__ __launch_bounds__(256)
void layernorm_k(const float* __restrict__ in, const float* __restrict__ g,
                 const float* __restrict__ bb, u16* __restrict__ out)
{
    const int token = blockIdx.x * 4 + (threadIdx.x >> 6);
    const int lane = threadIdx.x & 63;
    const float4 v = *reinterpret_cast<const float4*>(in + (size_t)token * 256 + lane * 4);
    float s  = v.x + v.y + v.z + v.w;
    float s2 = v.x * v.x + v.y * v.y + v.z * v.z + v.w * v.w;
#pragma unroll
    for (int m = 1; m < 64; m <<= 1) { s += __shfl_xor(s, m); s2 += __shfl_xor(s2, m); }
    const float mu  = s * (1.0f / 256.0f);
    const float var = s2 * (1.0f / 256.0f) - mu * mu;
    const float rs  = rsqrtf(var + 1e-5f);
    const float4 gv = *reinterpret_cast<const float4*>(g + lane * 4);
    const float4 bv = *reinterpret_cast<const float4*>(bb + lane * 4);
    ushort4 o;
    o.x = f2b((v.x - mu) * rs * gv.x + bv.x);
    o.y = f2b((v.y - mu) * rs * gv.y + bv.y);
    o.z = f2b((v.z - mu) * rs * gv.z + bv.z);
    o.w = f2b((v.w - mu) * rs * gv.w + bv.w);
    *reinterpret_cast<ushort4*>(out + (size_t)token * 256 + lane * 4) = o;
}

// ---------------------------------------------------------------------------
// Window attention: 1 wave per (window, head). Q pre-scaled. N=49 padded to 64.
// ---------------------------------------------------------------------------
__global__ __launch_bounds__(256)
void attn_win(const u16* __restrict__ qkv, const float* __restrict__ biasF,
              u16* __restrict__ outb)
{
    __shared__ u16 plds[4][64 * 72];
    const int wave = threadIdx.x >> 6, lane = threadIdx.x & 63;
    const int pair = blockIdx.x * 4 + wave;
    const int head = pair & 7, win = pair >> 3;
    const int lr = lane & 15, lg = lane >> 4;

    const u16* Q  = qkv + (size_t)pair * 1568;
    const u16* Kp = qkv + QK_ELEMS + (size_t)pair * 1568;
    const u16* Vt = qkv + V_OFF + (size_t)pair * 2048;

    bf16x8 qf[4], kf[4];
#pragma unroll
    for (int f = 0; f < 4; ++f) {
        int n = f * 16 + lr; n = n > 48 ? 48 : n;
        qf[f] = *reinterpret_cast<const bf16x8*>(Q  + n * 32 + lg * 8);
        kf[f] = *reinterpret_cast<const bf16x8*>(Kp + n * 32 + lg * 8);
    }
    f32x4 s[4][4] = {};
#pragma unroll
    for (int fm = 0; fm < 4; ++fm)
#pragma unroll
        for (int fn = 0; fn < 4; ++fn)
            s[fm][fn] = __builtin_amdgcn_mfma_f32_16x16x32_bf16(qf[fm], kf[fn], s[fm][fn], 0, 0, 0);

    const float* bh = biasF + head * 2401;
    u16* pl = &plds[wave][0];
#pragma unroll
    for (int fm = 0; fm < 4; ++fm) {
#pragma unroll
        for (int r = 0; r < 4; ++r) {
            const int row = fm * 16 + lg * 4 + r;
            const int brow = row > 48 ? 48 : row;
            float v[4];
#pragma unroll
            for (int fn = 0; fn < 4; ++fn) {
                const int col = fn * 16 + lr;
                const float bval = bh[brow * 49 + (col > 48 ? 48 : col)];
                v[fn] = (col > 48) ? -3.0e38f : (s[fm][fn][r] + bval);
            }
            float mx = fmaxf(fmaxf(v[0], v[1]), fmaxf(v[2], v[3]));
#pragma unroll
            for (int d = 1; d < 16; d <<= 1) mx = fmaxf(mx, __shfl_xor(mx, d));
            float p[4], sum = 0.f;
#pragma unroll
            for (int fn = 0; fn < 4; ++fn) {
                const int col = fn * 16 + lr;
                p[fn] = (col <= 48) ? __expf(v[fn] - mx) : 0.f;
                sum += p[fn];
            }
#pragma unroll
            for (int d = 1; d < 16; d <<= 1) sum += __shfl_xor(sum, d);
            const float rinv = 1.0f / sum;
#pragma unroll
            for (int fn = 0; fn < 4; ++fn)
                pl[row * 72 + fn * 16 + lr] = f2b(p[fn] * rinv);
        }
    }
    __syncthreads();

    f32x4 o[4][2] = {};
#pragma unroll
    for (int kc = 0; kc < 2; ++kc) {
        bf16x8 vf[2];
#pragma unroll
        for (int f2 = 0; f2 < 2; ++f2)
            vf[f2] = *reinterpret_cast<const bf16x8*>(Vt + (f2 * 16 + lr) * 64 + kc * 32 + lg * 8);
#pragma unroll
        for (int fm = 0; fm < 4; ++fm) {
            const bf16x8 pa = *reinterpret_cast<const bf16x8*>(pl + (fm * 16 + lr) * 72 + kc * 32 + lg * 8);
#pragma unroll
            for (int f2 = 0; f2 < 2; ++f2)
                o[fm][f2] = __builtin_amdgcn_mfma_f32_16x16x32_bf16(pa, vf[f2], o[fm][f2], 0, 0, 0);
        }
    }

    const int b = win >> 10, rem = win & 1023, wy = rem >> 5, wx = rem & 31;
#pragma unroll
    for (int fm = 0; fm < 4; ++fm) {
#pragma unroll
        for (int r = 0; r < 4; ++r) {
            const int tok = fm * 16 + lg * 4 + r;
            if (tok > 48) continue;
            const int y = wy * 7 + tok / 7, xx = wx * 7 + tok % 7;
            const size_t mrow = ((size_t)(b * 224 + y)) * 224 + xx;
#pragma unroll
            for (int f2 = 0; f2 < 2; ++f2)
                outb[mrow * 256 + head * 32 + f2 * 16 + lr] = f2b(o[fm][f2][r]);
        }
    }
}

// ---------------------------------------------------------------------------
// Helpers
// ---------------------------------------------------------------------------
__global__ __launch_bounds__(256)
void cvt_w(const float* __restrict__ qw, const float* __restrict__ pw,
           const float* __restrict__ f1, const float* __restrict__ f2,
           u16* __restrict__ outw)
{
    const int t = blockIdx.x * 256 + threadIdx.x;  // 786432 total
    float v;
    if (t < 196608) v = qw[t];
    else if (t < 262144) v = pw[t - 196608];
    else if (t < 524288) v = f1[t - 262144];
    else v = f2[t - 524288];
    outw[t] = f2b(v);
}

__global__ __launch_bounds__(256)
void bias_pre(const float* __restrict__ btab, const int* __restrict__ relidx,
              float* __restrict__ biasF)
{
    const int t = blockIdx.x * 256 + threadIdx.x;
    if (t >= 19208) return;
    const int head = t / 2401, ij = t % 2401;
    biasF[t] = btab[relidx[ij] * 8 + head];
}

__global__ __launch_bounds__(256)
void zero_vpad(u16* __restrict__ rbuf)
{
    const int t = blockIdx.x * 256 + threadIdx.x;  // 15728640 total
    if (t >= 15728640) return;
    const int pair = t / 480, q = t % 480;
    const int d = q / 15, nn = 49 + q % 15;
    rbuf[V_OFF + ((size_t)pair * 32 + d) * 64 + nn] = 0;
}

// ---------------------------------------------------------------------------
extern "C" void kernel_launch(void* const* d_in, const int* in_sizes, int n_in,
                              void* d_out, int out_size, void* d_ws, size_t ws_size,
                              hipStream_t stream)
{
    const float* x      = (const float*)d_in[0];
    const float* n1g    = (const float*)d_in[1];
    const float* n1b    = (const float*)d_in[2];
    const float* qkv_w  = (const float*)d_in[3];
    const float* qkv_b  = (const float*)d_in[4];
    const float* btab   = (const float*)d_in[5];
    const float* proj_w = (const float*)d_in[6];
    const float* proj_b = (const float*)d_in[7];
    const float* n2g    = (const float*)d_in[8];
    const float* n2b    = (const float*)d_in[9];
    const float* fc1_w  = (const float*)d_in[10];
    const float* fc1_b  = (const float*)d_in[11];
    const float* fc2_w  = (const float*)d_in[12];
    const float* fc2_b  = (const float*)d_in[13];
    const int*   relidx = (const int*)d_in[14];
    float* out = (float*)d_out;

    // workspace layout (min required ~445 MB):
    //  [0, 1572864)                    : bf16 weights
    //  [1572864, 1649696)              : bias_full f32 (8x49x49)
    //  [1650688, +102760448)           : A region (bf16 token x 256): h / attn_out / h2
    //  [104411136, ...)                : R region: Q|K|Vt (339.7 MB), reused as MLP hidden
    char* ws = (char*)d_ws;
    u16*   wbf   = (u16*)ws;
    float* biasF = (float*)(ws + 1572864);
    u16*   hbuf  = (u16*)(ws + 1650688);
    u16*   rbuf  = (u16*)(ws + 1650688 + 102760448);
    const size_t r_avail = ws_size - (1650688 + 102760448);

    const u16* Wq  = wbf;
    const u16* Wp  = wbf + 196608;
    const u16* Wf1 = wbf + 262144;
    const u16* Wf2 = wbf + 524288;

    cvt_w<<<3072, 256, 0, stream>>>(qkv_w, proj_w, fc1_w, fc2_w, wbf);
    bias_pre<<<76, 256, 0, stream>>>(btab, relidx, biasF);
    layernorm_k<<<50176, 256, 0, stream>>>(x, n1g, n1b, hbuf);
    zero_vpad<<<61440, 256, 0, stream>>>(rbuf);

    // QKV projection: M=200704, N=768, K=256
    gemm_bt<0><<<1568 * 6, 256, 0, stream>>>(hbuf, Wq, qkv_b, 6, 256, rbuf, nullptr, nullptr);
    // window attention
    attn_win<<<8192, 256, 0, stream>>>(rbuf, biasF, hbuf);
    // proj + residual -> d_out (x1)
    gemm_bt<1><<<1568 * 2, 256, 0, stream>>>(hbuf, Wp, proj_b, 2, 256, nullptr, out, x);
    // LN2: d_out -> h2
    layernorm_k<<<50176, 256, 0, stream>>>(out, n2g, n2b, hbuf);

    // MLP, chunked so hidden (bf16, M x 1024) fits in R region
    long rows_cap = (long)(r_avail / 2048);
    long rows_per = (rows_cap / 128) * 128;
    if (rows_per > TOKENS) rows_per = TOKENS;
    if (rows_per < 128) rows_per = 128;  // (ws too small would be fatal anyway)
    for (long r0 = 0; r0 < TOKENS; r0 += rows_per) {
        const long rows = (TOKENS - r0 < rows_per) ? (TOKENS - r0) : rows_per;
        gemm_bt<2><<<(int)((rows / 128) * 8), 256, 0, stream>>>(
            hbuf + r0 * 256, Wf1, fc1_b, 8, 256, rbuf, nullptr, nullptr);
        gemm_bt<3><<<(int)((rows / 128) * 2), 256, 0, stream>>>(
            rbuf, Wf2, fc2_b, 2, 1024, nullptr, out + r0 * 256, nullptr);
    }
}

// Round 2
// 1229.362 us; speedup vs baseline: 1.1408x; 1.1408x over previous
//
#include <hip/hip_runtime.h>

typedef unsigned short u16;
typedef __bf16 bf16x8 __attribute__((ext_vector_type(8)));
typedef float f32x4 __attribute__((ext_vector_type(4)));

#define TOKENS 200704
#define QK_ELEMS 51380224UL   // 32768 pairs * 49 * 32 (each of Q,K,V)

__device__ __forceinline__ u16 f2b(float f) {
    union { float f; unsigned u; } c; c.f = f;
    unsigned u = c.u;
    u += 0x7fffu + ((u >> 16) & 1u);   // round-to-nearest-even
    return (u16)(u >> 16);
}

#define GLDS(g, l) __builtin_amdgcn_global_load_lds( \
    (const __attribute__((address_space(1))) void*)(g), \
    (__attribute__((address_space(3))) void*)(l), 16, 0, 0)

// ---------------------------------------------------------------------------
// GEMM: C[m,n] = sum_k A[m,k] * W[n,k]  (A bf16 MxK row-major, W bf16 NxK row-major)
// 128x128 tile, BK=64, 256 threads (4 waves, 2x2), each wave 64x64 (4x4 frags).
// LDS XOR-swizzle: LDS[row][chunk] holds global chunk (chunk ^ (row&7));
// achieved by pre-swizzling the global source column for global_load_lds
// (linear LDS dest) and XOR-ing the chunk index on the ds_read side.
// EPI 0: qkv (+bias, q pre-scaled) -> (pair*49+pos)*32+d layout for Q,K,V
// EPI 1: proj (+bias +x residual -> f32 out)
// EPI 2: fc1 (+bias, exact GELU -> bf16)     EPI 3: fc2 (+bias, out += )
// ---------------------------------------------------------------------------
template<int EPI>
__global__ __launch_bounds__(256)
void gemm_bt(const u16* __restrict__ A, const u16* __restrict__ W,
             const float* __restrict__ bias, int nt, int K,
             u16* __restrict__ outb, float* __restrict__ outf,
             const float* __restrict__ res)
{
    __shared__ u16 As[128 * 64];
    __shared__ u16 Bs[128 * 64];
    const int tid  = threadIdx.x;
    const int wave = tid >> 6, lane = tid & 63;

    // bijective XCD-aware block swizzle (m204): contiguous chunk per XCD
    const int nwg = gridDim.x, bidO = blockIdx.x;
    const int qq = nwg >> 3, rr = nwg & 7;
    const int xcd = bidO & 7, idxx = bidO >> 3;
    const int bid = (xcd < rr) ? (xcd * (qq + 1) + idxx)
                               : (rr * (qq + 1) + (xcd - rr) * qq + idxx);

    const int bm = bid / nt, bn = bid % nt;
    const long m0 = (long)bm * 128;
    const int  n0 = bn * 128;
    const int wm = (wave >> 1) * 64, wn = (wave & 1) * 64;
    const int lr = lane & 15, lg = lane >> 4;
    const int crow   = lane >> 3;                       // row within 8-row chunk
    const int ccol_s = ((lane & 7) ^ crow) * 8;         // swizzled global col

    f32x4 acc[4][4] = {};

    for (int k0 = 0; k0 < K; k0 += 64) {
#pragma unroll
        for (int p = 0; p < 4; ++p) {
            const int i = wave * 4 + p;          // chunk 0..15 (wave-uniform)
            const int row = i * 8 + crow;
            GLDS(A + (m0 + row) * (long)K + k0 + ccol_s, As + i * 512);
            GLDS(W + (long)(n0 + row) * K + k0 + ccol_s, Bs + i * 512);
        }
        __syncthreads();
#pragma unroll
        for (int kk = 0; kk < 64; kk += 32) {
            bf16x8 af[4], bfr[4];
            const int swz = (lr & 7) * 8;
#pragma unroll
            for (int fm = 0; fm < 4; ++fm)
                af[fm] = *reinterpret_cast<const bf16x8*>(
                    As + (wm + fm * 16 + lr) * 64 + ((kk + lg * 8) ^ swz));
#pragma unroll
            for (int fn = 0; fn < 4; ++fn)
                bfr[fn] = *reinterpret_cast<const bf16x8*>(
                    Bs + (wn + fn * 16 + lr) * 64 + ((kk + lg * 8) ^ swz));
#pragma unroll
            for (int fm = 0; fm < 4; ++fm)
#pragma unroll
                for (int fn = 0; fn < 4; ++fn)
                    acc[fm][fn] = __builtin_amdgcn_mfma_f32_16x16x32_bf16(af[fm], bfr[fn], acc[fm][fn], 0, 0, 0);
        }
        __syncthreads();
    }

#pragma unroll
    for (int fm = 0; fm < 4; ++fm) {
#pragma unroll
        for (int r = 0; r < 4; ++r) {
            const long m = m0 + wm + fm * 16 + lg * 4 + r;
#pragma unroll
            for (int fn = 0; fn < 4; ++fn) {
                const int n = n0 + wn + fn * 16 + lr;
                const float v = acc[fm][fn][r];
                if (EPI == 0) {
                    const int mm = (int)m;
                    const int b = mm / 50176;
                    const int rem = mm % 50176;
                    const int y = rem / 224, x = rem % 224;
                    const int win = (b * 32 + y / 7) * 32 + x / 7;
                    const int pos = (y % 7) * 7 + (x % 7);
                    const int sec = n >> 8, hd = (n >> 5) & 7, d = n & 31;
                    const size_t pair = (size_t)win * 8 + hd;
                    const float sc = (sec == 0) ? 0.17677669529663687f : 1.0f;
                    outb[sec * QK_ELEMS + (pair * 49 + pos) * 32 + d] = f2b((v + bias[n]) * sc);
                } else if (EPI == 1) {
                    outf[m * 256 + n] = v + bias[n] + res[m * 256 + n];
                } else if (EPI == 2) {
                    const float t = v + bias[n];
                    const float g = 0.5f * t * (1.0f + erff(t * 0.7071067811865476f));
                    outb[m * 1024 + n] = f2b(g);
                } else {
                    outf[m * 256 + n] += v + bias[n];
                }
            }
        }
    }
}

// ---------------------------------------------------------------------------
// LayerNorm over C=256, f32 in -> bf16 out. 1 wave per token, 4 tokens/block.
// ---------------------------------------------------------------------------
__global__ __launch_bounds__(256)
void layernorm_k(const float* __restrict__ in, const float* __restrict__ g,
                 const float* __restrict__ bb, u16* __restrict__ out)
{
    const int token = blockIdx.x * 4 + (threadIdx.x >> 6);
    const int lane = threadIdx.x & 63;
    const float4 v = *reinterpret_cast<const float4*>(in + (size_t)token * 256 + lane * 4);
    float s  = v.x + v.y + v.z + v.w;
    float s2 = v.x * v.x + v.y * v.y + v.z * v.z + v.w * v.w;
#pragma unroll
    for (int m = 1; m < 64; m <<= 1) { s += __shfl_xor(s, m); s2 += __shfl_xor(s2, m); }
    const float mu  = s * (1.0f / 256.0f);
    const float var = s2 * (1.0f / 256.0f) - mu * mu;
    const float rs  = rsqrtf(var + 1e-5f);
    const float4 gv = *reinterpret_cast<const float4*>(g + lane * 4);
    const float4 bv = *reinterpret_cast<const float4*>(bb + lane * 4);
    ushort4 o;
    o.x = f2b((v.x - mu) * rs * gv.x + bv.x);
    o.y = f2b((v.y - mu) * rs * gv.y + bv.y);
    o.z = f2b((v.z - mu) * rs * gv.z + bv.z);
    o.w = f2b((v.w - mu) * rs * gv.w + bv.w);
    *reinterpret_cast<ushort4*>(out + (size_t)token * 256 + lane * 4) = o;
}

// ---------------------------------------------------------------------------
// Window attention: 1 wave per (window, head). Q pre-scaled. N=49 padded to 64.
// V arrives row-major [pos][d]; transposed per-wave through LDS into [d][pos]
// (pitch 72 u16 = 144 B -> ds_read_b128 gets 8 accesses/bank = conflict-free).
// ---------------------------------------------------------------------------
__global__ __launch_bounds__(256)
void attn_win(const u16* __restrict__ qkv, const float* __restrict__ biasF,
              u16* __restrict__ outb)
{
    __shared__ u16 plds[4][64 * 72];
    __shared__ u16 vlds[4][32 * 72];
    const int wave = threadIdx.x >> 6, lane = threadIdx.x & 63;
    const int pair = blockIdx.x * 4 + wave;
    const int head = pair & 7, win = pair >> 3;
    const int lr = lane & 15, lg = lane >> 4;

    const u16* Q  = qkv + (size_t)pair * 1568;
    const u16* Kp = qkv + QK_ELEMS + (size_t)pair * 1568;
    const u16* Vp = qkv + 2 * QK_ELEMS + (size_t)pair * 1568;

    // ---- stage V^T into LDS (zero the pad columns pos=49..63 first) ----
    u16* vl = &vlds[wave][0];
#pragma unroll
    for (int it = 0; it < 8; ++it) {
        const int idx = it * 64 + lane;            // 480 pad elems: 32 d x 15 pos
        if (idx < 480) vl[(idx / 15) * 72 + 49 + idx % 15] = 0;
    }
#pragma unroll
    for (int it = 0; it < 4; ++it) {
        const int idx = it * 64 + lane;            // 196 groups of 8 elems
        if (idx < 196) {
            const int pos = idx >> 2, dc = idx & 3;
            const uint4 vv = *reinterpret_cast<const uint4*>(Vp + pos * 32 + dc * 8);
            u16* dst = vl + (dc * 8) * 72 + pos;
            dst[0 * 72] = (u16)vv.x;  dst[1 * 72] = (u16)(vv.x >> 16);
            dst[2 * 72] = (u16)vv.y;  dst[3 * 72] = (u16)(vv.y >> 16);
            dst[4 * 72] = (u16)vv.z;  dst[5 * 72] = (u16)(vv.z >> 16);
            dst[6 * 72] = (u16)vv.w;  dst[7 * 72] = (u16)(vv.w >> 16);
        }
    }

    // ---- QK^T ----
    bf16x8 qf[4], kf[4];
#pragma unroll
    for (int f = 0; f < 4; ++f) {
        int n = f * 16 + lr; n = n > 48 ? 48 : n;
        qf[f] = *reinterpret_cast<const bf16x8*>(Q  + n * 32 + lg * 8);
        kf[f] = *reinterpret_cast<const bf16x8*>(Kp + n * 32 + lg * 8);
    }
    f32x4 s[4][4] = {};
#pragma unroll
    for (int fm = 0; fm < 4; ++fm)
#pragma unroll
        for (int fn = 0; fn < 4; ++fn)
            s[fm][fn] = __builtin_amdgcn_mfma_f32_16x16x32_bf16(qf[fm], kf[fn], s[fm][fn], 0, 0, 0);

    // ---- softmax (wave-parallel, 16-lane-group reduce) ----
    const float* bh = biasF + head * 2401;
    u16* pl = &plds[wave][0];
#pragma unroll
    for (int fm = 0; fm < 4; ++fm) {
#pragma unroll
        for (int r = 0; r < 4; ++r) {
            const int row = fm * 16 + lg * 4 + r;
            const int brow = row > 48 ? 48 : row;
            float v[4];
#pragma unroll
            for (int fn = 0; fn < 4; ++fn) {
                const int col = fn * 16 + lr;
                const float bval = bh[brow * 49 + (col > 48 ? 48 : col)];
                v[fn] = (col > 48) ? -3.0e38f : (s[fm][fn][r] + bval);
            }
            float mx = fmaxf(fmaxf(v[0], v[1]), fmaxf(v[2], v[3]));
#pragma unroll
            for (int d = 1; d < 16; d <<= 1) mx = fmaxf(mx, __shfl_xor(mx, d));
            float p[4], sum = 0.f;
#pragma unroll
            for (int fn = 0; fn < 4; ++fn) {
                const int col = fn * 16 + lr;
                p[fn] = (col <= 48) ? __expf(v[fn] - mx) : 0.f;
                sum += p[fn];
            }
#pragma unroll
            for (int d = 1; d < 16; d <<= 1) sum += __shfl_xor(sum, d);
            const float rinv = 1.0f / sum;
#pragma unroll
            for (int fn = 0; fn < 4; ++fn)
                pl[row * 72 + fn * 16 + lr] = f2b(p[fn] * rinv);
        }
    }
    __syncthreads();

    // ---- PV ----
    f32x4 o[4][2] = {};
#pragma unroll
    for (int kc = 0; kc < 2; ++kc) {
        bf16x8 vf[2];
#pragma unroll
        for (int f2 = 0; f2 < 2; ++f2)
            vf[f2] = *reinterpret_cast<const bf16x8*>(vl + (f2 * 16 + lr) * 72 + kc * 32 + lg * 8);
#pragma unroll
        for (int fm = 0; fm < 4; ++fm) {
            const bf16x8 pa = *reinterpret_cast<const bf16x8*>(pl + (fm * 16 + lr) * 72 + kc * 32 + lg * 8);
#pragma unroll
            for (int f2 = 0; f2 < 2; ++f2)
                o[fm][f2] = __builtin_amdgcn_mfma_f32_16x16x32_bf16(pa, vf[f2], o[fm][f2], 0, 0, 0);
        }
    }

    // ---- window-reverse store ----
    const int b = win >> 10, rem = win & 1023, wy = rem >> 5, wx = rem & 31;
#pragma unroll
    for (int fm = 0; fm < 4; ++fm) {
#pragma unroll
        for (int r = 0; r < 4; ++r) {
            const int tok = fm * 16 + lg * 4 + r;
            if (tok > 48) continue;
            const int y = wy * 7 + tok / 7, xx = wx * 7 + tok % 7;
            const size_t mrow = ((size_t)(b * 224 + y)) * 224 + xx;
#pragma unroll
            for (int f2 = 0; f2 < 2; ++f2)
                outb[mrow * 256 + head * 32 + f2 * 16 + lr] = f2b(o[fm][f2][r]);
        }
    }
}

// ---------------------------------------------------------------------------
// Helpers
// ---------------------------------------------------------------------------
__global__ __launch_bounds__(256)
void cvt_w(const float* __restrict__ qw, const float* __restrict__ pw,
           const float* __restrict__ f1, const float* __restrict__ f2,
           u16* __restrict__ outw)
{
    const int t = blockIdx.x * 256 + threadIdx.x;  // 786432 total
    float v;
    if (t < 196608) v = qw[t];
    else if (t < 262144) v = pw[t - 196608];
    else if (t < 524288) v = f1[t - 262144];
    else v = f2[t - 524288];
    outw[t] = f2b(v);
}

__global__ __launch_bounds__(256)
void bias_pre(const float* __restrict__ btab, const int* __restrict__ relidx,
              float* __restrict__ biasF)
{
    const int t = blockIdx.x * 256 + threadIdx.x;
    if (t >= 19208) return;
    const int head = t / 2401, ij = t % 2401;
    biasF[t] = btab[relidx[ij] * 8 + head];
}

// ---------------------------------------------------------------------------
extern "C" void kernel_launch(void* const* d_in, const int* in_sizes, int n_in,
                              void* d_out, int out_size, void* d_ws, size_t ws_size,
                              hipStream_t stream)
{
    const float* x      = (const float*)d_in[0];
    const float* n1g    = (const float*)d_in[1];
    const float* n1b    = (const float*)d_in[2];
    const float* qkv_w  = (const float*)d_in[3];
    const float* qkv_b  = (const float*)d_in[4];
    const float* btab   = (const float*)d_in[5];
    const float* proj_w = (const float*)d_in[6];
    const float* proj_b = (const float*)d_in[7];
    const float* n2g    = (const float*)d_in[8];
    const float* n2b    = (const float*)d_in[9];
    const float* fc1_w  = (const float*)d_in[10];
    const float* fc1_b  = (const float*)d_in[11];
    const float* fc2_w  = (const float*)d_in[12];
    const float* fc2_b  = (const float*)d_in[13];
    const int*   relidx = (const int*)d_in[14];
    float* out = (float*)d_out;

    // workspace layout:
    //  [0, 1572864)                    : bf16 weights
    //  [1572864, 1649696)              : bias_full f32 (8x49x49)
    //  [1650688, +102760448)           : A region (bf16 token x 256): h / attn_out / h2
    //  [104411136, ...)                : R region: Q|K|V (308.3 MB), reused as MLP hidden
    char* ws = (char*)d_ws;
    u16*   wbf   = (u16*)ws;
    float* biasF = (float*)(ws + 1572864);
    u16*   hbuf  = (u16*)(ws + 1650688);
    u16*   rbuf  = (u16*)(ws + 1650688 + 102760448);
    const size_t r_avail = ws_size - (1650688 + 102760448);

    const u16* Wq  = wbf;
    const u16* Wp  = wbf + 196608;
    const u16* Wf1 = wbf + 262144;
    const u16* Wf2 = wbf + 524288;

    cvt_w<<<3072, 256, 0, stream>>>(qkv_w, proj_w, fc1_w, fc2_w, wbf);
    bias_pre<<<76, 256, 0, stream>>>(btab, relidx, biasF);
    layernorm_k<<<50176, 256, 0, stream>>>(x, n1g, n1b, hbuf);

    // QKV projection: M=200704, N=768, K=256
    gemm_bt<0><<<1568 * 6, 256, 0, stream>>>(hbuf, Wq, qkv_b, 6, 256, rbuf, nullptr, nullptr);
    // window attention
    attn_win<<<8192, 256, 0, stream>>>(rbuf, biasF, hbuf);
    // proj + residual -> d_out (x1)
    gemm_bt<1><<<1568 * 2, 256, 0, stream>>>(hbuf, Wp, proj_b, 2, 256, nullptr, out, x);
    // LN2: d_out -> h2
    layernorm_k<<<50176, 256, 0, stream>>>(out, n2g, n2b, hbuf);

    // MLP, chunked so hidden (bf16, M x 1024) fits in R region
    long rows_cap = (long)(r_avail / 2048);
    long rows_per = (rows_cap / 128) * 128;
    if (rows_per > TOKENS) rows_per = TOKENS;
    if (rows_per < 128) rows_per = 128;
    for (long r0 = 0; r0 < TOKENS; r0 += rows_per) {
        const long rows = (TOKENS - r0 < rows_per) ? (TOKENS - r0) : rows_per;
        gemm_bt<2><<<(int)((rows / 128) * 8), 256, 0, stream>>>(
            hbuf + r0 * 256, Wf1, fc1_b, 8, 256, rbuf, nullptr, nullptr);
        gemm_bt<3><<<(int)((rows / 128) * 2), 256, 0, stream>>>(
            rbuf, Wf2, fc2_b, 2, 1024, nullptr, out + r0 * 256, nullptr);
    }
}